// Round 1
// 113.096 us; speedup vs baseline: 1.0012x; 1.0012x over previous
//
#include <hip/hip_runtime.h>
#include <stdint.h>

// Problem constants (fixed by reference)
#define N_IMG   16
#define C_IN    256
#define H_IN    32
#define W_IN    32
#define OH      30
#define OW      30
#define K_SEL   1152                   // C*KH*KW/2
#define OUTC    512
#define RY_TOT  (N_IMG * OH)           // 480 (n,y) rows
#define M_HAT   (RY_TOT * 32)          // 15360 = padded M (ow 30 -> 32)
#define X_ELEMS (N_IMG * C_IN * H_IN * W_IN)   // 4194304
#define OUT_SP  (OH * OW)              // 900
#define CHW     (C_IN * H_IN * W_IN)   // 262144

#define TO      128                    // o-tile
#define TM      64                     // m-tile = 2 ry rows x 32 xw
#define NMT     (M_HAT / TM)           // 240
#define NOT     (OUTC / TO)            // 4
#define BSTR    40                     // Bs row stride (shorts): 80B rows -> 16B-aligned b128,
                                       // read 2-way (free), write 4-way (1.58x)
#define KITER   (K_SEL / 32)           // 36

typedef float f32x4  __attribute__((ext_vector_type(4)));
typedef short bf16x8 __attribute__((ext_vector_type(8)));   // 8 bf16 = 4 VGPRs

__device__ __forceinline__ unsigned short f2bf(float f) {   // fp32 -> bf16 RNE
    unsigned int u = __float_as_uint(f);
    u += 0x7FFFu + ((u >> 16) & 1u);
    return (unsigned short)(u >> 16);
}

// async global->LDS, 16B/lane; LDS dst wave-uniform base, HW adds lane*16.
__device__ __forceinline__ void gl_lds16(const void* g, void* lds) {
    __builtin_amdgcn_global_load_lds(
        (const __attribute__((address_space(1))) unsigned int*)g,
        (__attribute__((address_space(3))) unsigned int*)lds,
        16, 0, 0);
}

// ---------------------------------------------------------------------------
// Prep: koff decode + coalesced LDS-tile transpose w(K_SEL x OUTC fp32) ->
// wT(OUTC x K_SEL bf16). Grid (36 s-tiles, 16 o-tiles) x 256 thr.
// ---------------------------------------------------------------------------
__global__ void prep_kernel(const int* __restrict__ idx, const float* __restrict__ w,
                            int* __restrict__ koff, unsigned short* __restrict__ wT) {
    __shared__ float tile[32][33];                 // +1 pad: phase1 conflict-free
    const int bx = blockIdx.x, by = blockIdx.y, t = threadIdx.x;

    if (by == 0) {                                 // fold koff decode into first row
        int k = bx * 256 + t;
        if (k < K_SEL) {
            int v = idx[k];
            int c = v / 9, rem = v - c * 9;
            int i = rem / 3, j = rem - i * 3;
            koff[k] = c * (H_IN * W_IN) + i * W_IN + j;
        }
    }
    const int s0 = bx * 32, o0 = by * 32;
    const int oc = t & 31, sg = t >> 5;
#pragma unroll
    for (int i = 0; i < 4; ++i) {                  // coalesced 128B reads along o
        int sl = sg * 4 + i;
        tile[sl][oc] = w[(s0 + sl) * OUTC + o0 + oc];
    }
    __syncthreads();
    const int ol = t >> 3, sq = t & 7;             // write along s: coalesced
    unsigned int u0 = (unsigned int)f2bf(tile[sq * 4 + 0][ol]) |
                      ((unsigned int)f2bf(tile[sq * 4 + 1][ol]) << 16);
    unsigned int u1 = (unsigned int)f2bf(tile[sq * 4 + 2][ol]) |
                      ((unsigned int)f2bf(tile[sq * 4 + 3][ol]) << 16);
    uint2 pk; pk.x = u0; pk.y = u1;
    *reinterpret_cast<uint2*>(&wT[(size_t)(o0 + ol) * K_SEL + s0 + sq * 4]) = pk;
}

// ---------------------------------------------------------------------------
// Fused GEMM: out[n,o,y,x] = sum_k wT[o][k] * x[n, koff[k] + y*32 + xw]
// Tile 128o x 64m, BK=32, 960 blocks. NEW vs 113µs version:
//  * As/Bs double-buffered -> 1 barrier per k-step (was 2), and tile kt+1's
//    gl_lds is issued a full iteration before its consumption, so the
//    vmcnt(0) drain at the barrier lands after the MFMA phase, not before it.
//  * x-gather pipelined 2 tiles deep (gather kt+2 while packing kt+1,
//    computing kt) - prefetch latency now genuinely overlapped.
//  * As chunk-XOR swizzle (both-sides: pre-swizzled global source keeps the
//    gl_lds dest linear; same XOR on the loop-invariant read address) kills
//    the 8-way bank conflict on the a-fragment ds_read_b128.
//  * koS read as int4 (1 ds_read_b128 instead of 4 b32 per k-step).
// ot = bid/240: o-siblings 240 apart -> same XCD (240%8==0) -> x L2 reuse.
// ---------------------------------------------------------------------------
__global__ __launch_bounds__(256, 4)
void gemm_kernel(const unsigned short* __restrict__ wT, const float* __restrict__ x,
                 const int* __restrict__ koff, float* __restrict__ out) {
    __shared__ __align__(16) unsigned short As[2][TO * 32];    // rows = o-local, k-contig
    __shared__ __align__(16) unsigned short Bs[2][TM * BSTR];  // rows = m-local, padded
    __shared__ int koS[K_SEL];

    const int t    = threadIdx.x;
    const int wave = t >> 6;
    const int lane = t & 63;
    const int quad = lane >> 4;
    const int lo   = lane & 15;

    const int bid = blockIdx.x;
    const int mt  = bid % NMT;
    const int ot  = bid / NMT;
    const int oBase = ot * TO;
    const int mBase = mt * TM;

    for (int i = t; i < K_SEL; i += 256) koS[i] = koff[i];

    const int xw  = t & 31;                        // spatial lane within ry row
    int basex[2];
#pragma unroll
    for (int ry = 0; ry < 2; ++ry) {
        int ryg = mt * 2 + ry;
        int n = ryg / 30, y = ryg - n * 30;
        basex[ry] = n * CHW + y * W_IN + xw;
    }

    const int kq4 = t >> 5;                        // 0..7 -> 4 k's each
    const int ks  = kq4 * 4;

    // A staging: each wave owns 32 o-rows; 2 gl_lds16 of 1KB each per buffer.
    // Source pre-swizzled so linear LDS holds chunk c ^ ((row>>1)&3).
    const int lrow = lane >> 2, csw = (lane & 3) ^ ((lrow >> 1) & 3);
    const unsigned short* wrow0 = wT + (size_t)(oBase + wave * 32 + lrow) * K_SEL + csw * 8;
    const unsigned short* wrow1 = wT + (size_t)(oBase + wave * 32 + 16 + lrow) * K_SEL + csw * 8;
    unsigned short* lA0 = &As[0][(wave * 32) * 32];
    unsigned short* lA1 = &As[1][(wave * 32) * 32];

    // Loop-invariant read addresses (same XOR applied on the chunk index).
    const int aswz = quad ^ ((lo >> 1) & 3);
    const unsigned short* aB[2] = {
        &As[0][(wave * 32 + lo) * 32 + aswz * 8],
        &As[1][(wave * 32 + lo) * 32 + aswz * 8] };
    const unsigned short* bB[2] = {
        &Bs[0][lo * BSTR + quad * 8],
        &Bs[1][lo * BSTR + quad * 8] };
    unsigned short* bW[2] = {
        &Bs[0][xw * BSTR + ks],
        &Bs[1][xw * BSTR + ks] };

    __syncthreads();                               // koS ready

    f32x4 acc[2][4] = {};
    float v[2][2][4];                              // v[tile&1][ry][j]

    // ---- prologue: tile 0 fully staged, tile 1 gathered ----
    gl_lds16(wrow0, lA0);
    gl_lds16(wrow1, lA0 + 16 * 32);
    {
        int4 k4 = *(const int4*)&koS[ks];
#pragma unroll
        for (int ry = 0; ry < 2; ++ry)
#pragma unroll
            for (int j = 0; j < 4; ++j) {
                int g = basex[ry] + ((const int*)&k4)[j];
                g = min(g, X_ELEMS - 1);           // xw>=30 garbage, masked at store
                v[0][ry][j] = x[g];
            }
    }
#pragma unroll
    for (int ry = 0; ry < 2; ++ry) {
        unsigned int u0 = (unsigned int)f2bf(v[0][ry][0]) |
                          ((unsigned int)f2bf(v[0][ry][1]) << 16);
        unsigned int u1 = (unsigned int)f2bf(v[0][ry][2]) |
                          ((unsigned int)f2bf(v[0][ry][3]) << 16);
        uint2 pk; pk.x = u0; pk.y = u1;
        *reinterpret_cast<uint2*>(bW[0] + ry * 32 * BSTR) = pk;
    }
    {
        int4 k4 = *(const int4*)&koS[32 + ks];
#pragma unroll
        for (int ry = 0; ry < 2; ++ry)
#pragma unroll
            for (int j = 0; j < 4; ++j) {
                int g = basex[ry] + ((const int*)&k4)[j];
                g = min(g, X_ELEMS - 1);
                v[1][ry][j] = x[g];
            }
    }
    __syncthreads();                               // As[0]+Bs[0] visible

    // ---- main loop: 1 barrier per k-step ----
#pragma unroll 2
    for (int kt = 0; kt < KITER; ++kt) {
        const int p = kt & 1, q = p ^ 1;
        unsigned short* lAq = q ? lA1 : lA0;

        // 1) issue next-tile A stage (consumed after NEXT barrier)
        if (kt + 1 < KITER) {
            const int k1 = (kt + 1) * 32;
            gl_lds16(wrow0 + k1, lAq);
            gl_lds16(wrow1 + k1, lAq + 16 * 32);
        }
        // 2) issue gather for tile kt+2 (packed next iteration)
        if (kt + 2 < KITER) {
            const int k2 = (kt + 2) * 32;
            int4 k4 = *(const int4*)&koS[k2 + ks];
#pragma unroll
            for (int ry = 0; ry < 2; ++ry)
#pragma unroll
                for (int j = 0; j < 4; ++j) {
                    int g = basex[ry] + ((const int*)&k4)[j];
                    g = min(g, X_ELEMS - 1);
                    v[p][ry][j] = x[g];
                }
        }
        // 3) pack tile kt+1's gathered x -> Bs[q]
        if (kt + 1 < KITER) {
#pragma unroll
            for (int ry = 0; ry < 2; ++ry) {
                unsigned int u0 = (unsigned int)f2bf(v[q][ry][0]) |
                                  ((unsigned int)f2bf(v[q][ry][1]) << 16);
                unsigned int u1 = (unsigned int)f2bf(v[q][ry][2]) |
                                  ((unsigned int)f2bf(v[q][ry][3]) << 16);
                uint2 pk; pk.x = u0; pk.y = u1;
                *reinterpret_cast<uint2*>(bW[q] + ry * 32 * BSTR) = pk;
            }
        }
        // 4) compute tile kt from buffer p
        bf16x8 a[2], b[4];
#pragma unroll
        for (int ms = 0; ms < 2; ++ms)
            a[ms] = *(const bf16x8*)(aB[p] + ms * 16 * 32);
#pragma unroll
        for (int ns = 0; ns < 4; ++ns)
            b[ns] = *(const bf16x8*)(bB[p] + ns * 16 * BSTR);
#pragma unroll
        for (int ms = 0; ms < 2; ++ms)
#pragma unroll
            for (int ns = 0; ns < 4; ++ns)
                acc[ms][ns] = __builtin_amdgcn_mfma_f32_16x16x32_bf16(
                    a[ms], b[ns], acc[ms][ns], 0, 0, 0);
        __syncthreads();                           // buffer q ready / buffer p free
    }

    // Epilogue (verified R1 mapping): D row = o (quad*4+r), col = m (lane&15).
#pragma unroll
    for (int ns = 0; ns < 4; ++ns) {
        const int mh  = mBase + ns * 16 + lo;
        const int xwe = mh & 31;
        const int ryg = mh >> 5;
        const int n = ryg / 30, y = ryg - n * 30;
        if (xwe < OW) {
            const size_t ob = (size_t)n * (OUTC * OUT_SP) + (size_t)y * OW + xwe;
#pragma unroll
            for (int ms = 0; ms < 2; ++ms) {
                const int o0 = oBase + wave * 32 + ms * 16 + quad * 4;
#pragma unroll
                for (int r = 0; r < 4; ++r)
                    out[ob + (size_t)(o0 + r) * OUT_SP] = acc[ms][ns][r];
            }
        }
    }
}

// ---------------------------------------------------------------------------
extern "C" void kernel_launch(void* const* d_in, const int* in_sizes, int n_in,
                              void* d_out, int out_size, void* d_ws, size_t ws_size,
                              hipStream_t stream) {
    const float* x   = (const float*)d_in[0];
    const float* w   = (const float*)d_in[1];
    const int*   idx = (const int*)d_in[2];
    float*       out = (float*)d_out;

    // ws layout: koff 4608B | wT bf16 1179648B  (~1.2 MB total)
    char* ws = (char*)d_ws;
    int*            koff = (int*)ws;
    unsigned short* wT   = (unsigned short*)(ws + 4608);

    prep_kernel<<<dim3(K_SEL / 32, OUTC / 32), dim3(256), 0, stream>>>(idx, w, koff, wT);
    gemm_kernel<<<dim3(NMT * NOT), dim3(256), 0, stream>>>(wT, x, koff, out);
}